// Round 5
// baseline (56.557 us; speedup 1.0000x reference)
//
#include <hip/hip_runtime.h>

// CRF NLL, two-kernel scheme (math identical to the verified round-4 fused kernel).
// K1: emissions e=(X·W^T)/ln2 as f32 -> d_ws [163840][32], one 16-row MFMA tile per wave.
// K2: MFMA-matvec forward recursion, 1 wave = 16 batch elems; e read as f32x4 from d_ws.

typedef float f32x4 __attribute__((ext_vector_type(4)));
typedef __bf16 bf16x8 __attribute__((ext_vector_type(8)));

#define C_SCALE 1.4426950408889634f  // 1/ln2
#define LN2 0.6931471805599453f
#define NEGF -3.0e38f

__device__ __forceinline__ unsigned short f2bf(float f) {
    unsigned u = __float_as_uint(f);
    u += 0x7fffu + ((u >> 16) & 1u);   // RNE
    return (unsigned short)(u >> 16);
}

union ABu { unsigned int w[4]; bf16x8 b; unsigned short u[8]; };

__device__ __forceinline__ bf16x8 pack_bf8(f32x4 a, f32x4 b) {
    ABu r;
    r.u[0] = f2bf(a[0]); r.u[1] = f2bf(a[1]); r.u[2] = f2bf(a[2]); r.u[3] = f2bf(a[3]);
    r.u[4] = f2bf(b[0]); r.u[5] = f2bf(b[1]); r.u[6] = f2bf(b[2]); r.u[7] = f2bf(b[3]);
    return r.b;
}

// ---------------- K1: emissions (grid 2560 x 256, one tile per wave) ----------------
__global__ __launch_bounds__(256) void emis_kernel(
    const float* __restrict__ X, const float* __restrict__ W,
    float* __restrict__ e_ws)
{
    const int tid = threadIdx.x;
    const int w = tid >> 6, l = tid & 63;
    const int c0 = l & 15, kg = l >> 4;

    // W as bf16 B-fragments (verified): B[k][col]=W[col][k], col=lane&15, k=kg*8+j
    ABu bfrag[4][2];
    {
        const int koff = kg * 8;
        #pragma unroll
        for (int kk = 0; kk < 4; ++kk) {
            #pragma unroll
            for (int nt = 0; nt < 2; ++nt) {
                const int col = nt * 16 + c0;
                ABu f;
                if (col < 26) {
                    const float* wp = W + col * 128 + kk * 32 + koff;
                    f32x4 w0 = *(const f32x4*)wp;
                    f32x4 w1 = *(const f32x4*)(wp + 4);
                    f.b = pack_bf8(w0, w1);
                } else {
                    f.w[0] = f.w[1] = f.w[2] = f.w[3] = 0u;
                }
                bfrag[kk][nt] = f;
            }
        }
    }

    const int rbase = blockIdx.x * 64 + w * 16;   // this wave's 16 rows
    const float* xp = X + (long)(rbase + c0) * 128 + kg * 8;
    f32x4 acc0 = {0.f,0.f,0.f,0.f}, acc1 = {0.f,0.f,0.f,0.f};
    #pragma unroll
    for (int kk = 0; kk < 4; ++kk) {
        f32x4 x0 = *(const f32x4*)(xp + kk * 32);
        f32x4 x1 = *(const f32x4*)(xp + kk * 32 + 4);
        bf16x8 a = pack_bf8(x0, x1);
        acc0 = __builtin_amdgcn_mfma_f32_16x16x32_bf16(a, bfrag[kk][0].b, acc0, 0, 0, 0);
        acc1 = __builtin_amdgcn_mfma_f32_16x16x32_bf16(a, bfrag[kk][1].b, acc1, 0, 0, 0);
    }
    // C/D: col=lane&15, row=kg*4+i  [verified]
    #pragma unroll
    for (int i = 0; i < 4; ++i) {
        const long row = rbase + kg * 4 + i;
        e_ws[row * 32 + c0]      = acc0[i] * C_SCALE;
        e_ws[row * 32 + 16 + c0] = acc1[i] * C_SCALE;
    }
}

// ---------------- K2: recursion (grid 512 x 64, one wave = 16 elems) ----------------
__global__ __launch_bounds__(64) void crf_fwd_kernel(
    const float* __restrict__ e_ws, const int* __restrict__ Y,
    const float* __restrict__ T, float* __restrict__ out)
{
    const int l = threadIdx.x;
    const int g = l >> 4, c = l & 15;
    const int elem = blockIdx.x * 16 + c;

    // A-fragments: A[m][k'] = E[pi(k')][m], pi(8g+jj) = 4g+(jj&3)+16*(jj>>2)  [verified]
    ABu A0, A1;
    #pragma unroll
    for (int jj = 0; jj < 8; ++jj) {
        const int kp = 4 * g + (jj & 3) + ((jj >> 2) << 4);
        float v0 = 0.f, v1 = 0.f;
        if (kp < 26) {
            v0 = __builtin_amdgcn_exp2f(T[kp * 26 + c] * C_SCALE);
            if (16 + c < 26) v1 = __builtin_amdgcn_exp2f(T[kp * 26 + 16 + c] * C_SCALE);
        }
        A0.u[jj] = f2bf(v0);
        A1.u[jj] = f2bf(v1);
    }

    const bool ok0 = (16 + 4 * g + 0) < 26;
    const bool ok1 = (16 + 4 * g + 1) < 26;
    const bool ok2 = (16 + 4 * g + 2) < 26;
    const bool ok3 = (16 + 4 * g + 3) < 26;

    const float* eb = e_ws + (long)elem * 640 + 4 * g;   // elem*20*32, this lane's quad

    f32x4 s0 = *(const f32x4*)(eb);
    f32x4 s1 = *(const f32x4*)(eb + 16);
    if (!ok0) s1[0] = NEGF;
    if (!ok1) s1[1] = NEGF;
    if (!ok2) s1[2] = NEGF;
    if (!ok3) s1[3] = NEGF;

    const f32x4 z = {0.f, 0.f, 0.f, 0.f};
    #pragma unroll 1
    for (int m = 0; m < 19; ++m) {
        float mx = fmaxf(fmaxf(fmaxf(s0[0], s0[1]), fmaxf(s0[2], s0[3])),
                         fmaxf(fmaxf(s1[0], s1[1]), fmaxf(s1[2], s1[3])));
        mx = fmaxf(mx, __shfl_xor(mx, 16, 64));
        mx = fmaxf(mx, __shfl_xor(mx, 32, 64));
        ABu B;
        B.u[0] = f2bf(__builtin_amdgcn_exp2f(s0[0] - mx));
        B.u[1] = f2bf(__builtin_amdgcn_exp2f(s0[1] - mx));
        B.u[2] = f2bf(__builtin_amdgcn_exp2f(s0[2] - mx));
        B.u[3] = f2bf(__builtin_amdgcn_exp2f(s0[3] - mx));
        B.u[4] = f2bf(__builtin_amdgcn_exp2f(s1[0] - mx));
        B.u[5] = f2bf(__builtin_amdgcn_exp2f(s1[1] - mx));
        B.u[6] = f2bf(__builtin_amdgcn_exp2f(s1[2] - mx));
        B.u[7] = f2bf(__builtin_amdgcn_exp2f(s1[3] - mx));
        f32x4 D0 = __builtin_amdgcn_mfma_f32_16x16x32_bf16(A0.b, B.b, z, 0, 0, 0);
        f32x4 D1 = __builtin_amdgcn_mfma_f32_16x16x32_bf16(A1.b, B.b, z, 0, 0, 0);
        const float* em = eb + (m + 1) * 32;
        f32x4 e0 = *(const f32x4*)(em);
        f32x4 e1 = *(const f32x4*)(em + 16);
        #pragma unroll
        for (int i = 0; i < 4; ++i)
            s0[i] = mx + __builtin_amdgcn_logf(D0[i]) + e0[i];
        s1[0] = ok0 ? (mx + __builtin_amdgcn_logf(D1[0]) + e1[0]) : NEGF;
        s1[1] = ok1 ? (mx + __builtin_amdgcn_logf(D1[1]) + e1[1]) : NEGF;
        s1[2] = ok2 ? (mx + __builtin_amdgcn_logf(D1[2]) + e1[2]) : NEGF;
        s1[3] = ok3 ? (mx + __builtin_amdgcn_logf(D1[3]) + e1[3]) : NEGF;
    }

    // logZ per column c
    float mx2 = fmaxf(fmaxf(fmaxf(s0[0], s0[1]), fmaxf(s0[2], s0[3])),
                      fmaxf(fmaxf(s1[0], s1[1]), fmaxf(s1[2], s1[3])));
    mx2 = fmaxf(mx2, __shfl_xor(mx2, 16, 64));
    mx2 = fmaxf(mx2, __shfl_xor(mx2, 32, 64));
    float sm = __builtin_amdgcn_exp2f(s0[0] - mx2) + __builtin_amdgcn_exp2f(s0[1] - mx2)
             + __builtin_amdgcn_exp2f(s0[2] - mx2) + __builtin_amdgcn_exp2f(s0[3] - mx2)
             + __builtin_amdgcn_exp2f(s1[0] - mx2) + __builtin_amdgcn_exp2f(s1[1] - mx2)
             + __builtin_amdgcn_exp2f(s1[2] - mx2) + __builtin_amdgcn_exp2f(s1[3] - mx2);
    sm += __shfl_xor(sm, 16, 64);
    sm += __shfl_xor(sm, 32, 64);
    const float logZ2 = mx2 + __builtin_amdgcn_logf(sm);

    // node + edge: lane (g,c) covers elem's timesteps 5g..5g+4
    const int ebase = elem * 20;
    float nd2 = 0.f, edn = 0.f;
    {
        int y[6];
        #pragma unroll
        for (int t = 0; t < 5; ++t) y[t] = Y[ebase + 5 * g + t];
        y[5] = (g < 3) ? Y[ebase + 5 * g + 5] : 0;
        #pragma unroll
        for (int t = 0; t < 5; ++t) {
            const int m = 5 * g + t;
            nd2 += e_ws[(long)(ebase + m) * 32 + y[t]];
            if (m < 19) edn += T[y[t] * 26 + y[t + 1]];
        }
    }

    float v = -LN2 * nd2 - edn;
    if (g == 0) v += LN2 * logZ2;
    #pragma unroll
    for (int d = 1; d <= 32; d <<= 1) v += __shfl_xor(v, d, 64);
    if (l == 0) atomicAdd(out, v);
}

extern "C" void kernel_launch(void* const* d_in, const int* in_sizes, int n_in,
                              void* d_out, int out_size, void* d_ws, size_t ws_size,
                              hipStream_t stream) {
    const float* X = (const float*)d_in[0];
    const int*   Y = (const int*)d_in[1];
    const float* W = (const float*)d_in[2];
    const float* T = (const float*)d_in[3];
    float* out = (float*)d_out;
    float* e_ws = (float*)d_ws;

    const int rows = in_sizes[0] / 128;    // 163840
    const int nblk1 = rows / 64;           // 2560
    const int nblk2 = (rows / 20) / 16;    // 512

    hipMemsetAsync(out, 0, sizeof(float), stream);
    emis_kernel<<<nblk1, 256, 0, stream>>>(X, W, e_ws);
    crf_fwd_kernel<<<nblk2, 64, 0, stream>>>(e_ws, Y, T, out);
}

// Round 7
// 40.030 us; speedup vs baseline: 1.4129x; 1.4129x over previous
//
#include <hip/hip_runtime.h>

// CRF NLL fused kernel, v5 = round-4 verified math + X-prefetch + wave-1 node/edge.
// NO inline asm anywhere (rounds 3/6 NaN'd with cvtpk asm; bisecting it out).
// Phase A: emissions e=(X·W^T)/ln2 f32 into LDS via bf16 MFMA; all 40 X-loads issued
//          up front per wave (deep vmcnt pipeline), packs via f2bf (pure VALU).
// Phase B: wave 0 = MFMA-matvec recursion (verified), wave 1 = node/edge potentials,
//          waves 2-3 exit after the barrier.

typedef float f32x4 __attribute__((ext_vector_type(4)));
typedef __bf16 bf16x8 __attribute__((ext_vector_type(8)));

#define C_SCALE 1.4426950408889634f  // 1/ln2
#define LN2 0.6931471805599453f
#define NEGF -3.0e38f

__device__ __forceinline__ unsigned short f2bf(float f) {
    unsigned u = __float_as_uint(f);
    u += 0x7fffu + ((u >> 16) & 1u);   // RNE
    return (unsigned short)(u >> 16);
}

union ABu { unsigned int w[4]; bf16x8 b; unsigned short u[8]; };

__device__ __forceinline__ bf16x8 pack_bf8(f32x4 a, f32x4 b) {
    ABu r;
    r.u[0] = f2bf(a[0]); r.u[1] = f2bf(a[1]); r.u[2] = f2bf(a[2]); r.u[3] = f2bf(a[3]);
    r.u[4] = f2bf(b[0]); r.u[5] = f2bf(b[1]); r.u[6] = f2bf(b[2]); r.u[7] = f2bf(b[3]);
    return r.b;
}

__global__ __launch_bounds__(256) void crf_kernel(
    const float* __restrict__ X, const int* __restrict__ Y,
    const float* __restrict__ W, const float* __restrict__ T,
    float* __restrict__ out, int n_elems)
{
    __shared__ float e_lds[320 * 33];   // scaled emissions, stride 33
    __shared__ float t_lds[26 * 26];    // T natural domain

    const int tid = threadIdx.x;
    const int w   = tid >> 6;
    const int l   = tid & 63;
    const int c0  = l & 15, kg = l >> 4;

    // ---- Phase A: issue ALL X loads up front (deep pipeline) ----
    f32x4 xv[5][8];
    #pragma unroll
    for (int t = 0; t < 5; ++t) {
        const float* xp = X + ((long)blockIdx.x * 320 + w * 80 + t * 16 + c0) * 128 + kg * 8;
        #pragma unroll
        for (int kk = 0; kk < 4; ++kk) {
            xv[t][2 * kk]     = *(const f32x4*)(xp + kk * 32);
            xv[t][2 * kk + 1] = *(const f32x4*)(xp + kk * 32 + 4);
        }
    }

    for (int i = tid; i < 676; i += 256) t_lds[i] = T[i];

    // W as bf16 B-fragments (layout verified): B[k][col]=W[col][k], col=lane&15, k=kg*8+j
    ABu bfrag[4][2];
    {
        const int koff = kg * 8;
        #pragma unroll
        for (int kk = 0; kk < 4; ++kk) {
            #pragma unroll
            for (int nt = 0; nt < 2; ++nt) {
                const int col = nt * 16 + c0;
                ABu f;
                if (col < 26) {
                    const float* wp = W + col * 128 + kk * 32 + koff;
                    f32x4 w0 = *(const f32x4*)wp;
                    f32x4 w1 = *(const f32x4*)(wp + 4);
                    f.b = pack_bf8(w0, w1);
                } else {
                    f.w[0] = f.w[1] = f.w[2] = f.w[3] = 0u;
                }
                bfrag[kk][nt] = f;
            }
        }
    }

    // ---- Phase A compute: 5 tiles ----
    {
        const int rbase = w * 80;
        #pragma unroll
        for (int t = 0; t < 5; ++t) {
            f32x4 acc0 = {0.f,0.f,0.f,0.f}, acc1 = {0.f,0.f,0.f,0.f};
            #pragma unroll
            for (int kk = 0; kk < 4; ++kk) {
                bf16x8 a = pack_bf8(xv[t][2 * kk], xv[t][2 * kk + 1]);
                acc0 = __builtin_amdgcn_mfma_f32_16x16x32_bf16(a, bfrag[kk][0].b, acc0, 0, 0, 0);
                acc1 = __builtin_amdgcn_mfma_f32_16x16x32_bf16(a, bfrag[kk][1].b, acc1, 0, 0, 0);
            }
            // C/D: col=lane&15, row=kg*4+i  [verified]
            #pragma unroll
            for (int i = 0; i < 4; ++i) {
                const int rr = rbase + t * 16 + kg * 4 + i;
                e_lds[rr * 33 + c0]      = acc0[i] * C_SCALE;
                e_lds[rr * 33 + 16 + c0] = acc1[i] * C_SCALE;
            }
        }
    }
    __syncthreads();

    const int g = l >> 4, c = l & 15;
    const int elem = blockIdx.x * 16 + c;

    // ---- Wave 1: node + edge potentials (overlaps wave 0's recursion) ----
    if (w == 1) {
        const int ebase = elem * 20;
        float nd2 = 0.f, edn = 0.f;
        int y[6];
        #pragma unroll
        for (int t = 0; t < 5; ++t) y[t] = Y[ebase + 5 * g + t];
        y[5] = (g < 3) ? Y[ebase + 5 * g + 5] : 0;
        #pragma unroll
        for (int t = 0; t < 5; ++t) {
            const int m = 5 * g + t;
            nd2 += e_lds[(c * 20 + m) * 33 + y[t]];
            if (m < 19) edn += t_lds[y[t] * 26 + y[t + 1]];
        }
        float v = -LN2 * nd2 - edn;
        #pragma unroll
        for (int d = 1; d <= 32; d <<= 1) v += __shfl_xor(v, d, 64);
        if (l == 0) atomicAdd(out, v);
        return;
    }
    if (w != 0) return;

    // ---- Wave 0: MFMA-matvec recursion (verified round-4 math, unchanged) ----
    // A-fragments: A[m][k'] = E[pi(k')][m], pi(8g+jj) = 4g+(jj&3)+16*(jj>>2)
    ABu A0, A1;
    #pragma unroll
    for (int jj = 0; jj < 8; ++jj) {
        const int kp = 4 * g + (jj & 3) + ((jj >> 2) << 4);
        float v0 = 0.f, v1 = 0.f;
        if (kp < 26) {
            v0 = __builtin_amdgcn_exp2f(t_lds[kp * 26 + c] * C_SCALE);
            if (16 + c < 26) v1 = __builtin_amdgcn_exp2f(t_lds[kp * 26 + 16 + c] * C_SCALE);
        }
        A0.u[jj] = f2bf(v0);
        A1.u[jj] = f2bf(v1);
    }

    const bool ok0 = (16 + 4 * g + 0) < 26;
    const bool ok1 = (16 + 4 * g + 1) < 26;
    const bool ok2 = (16 + 4 * g + 2) < 26;
    const bool ok3 = (16 + 4 * g + 3) < 26;

    const float* eb = e_lds + c * 660 + 4 * g;   // c*20*33, this lane's label quad

    f32x4 s0, s1;
    #pragma unroll
    for (int i = 0; i < 4; ++i) { s0[i] = eb[i]; s1[i] = eb[16 + i]; }
    if (!ok0) s1[0] = NEGF;
    if (!ok1) s1[1] = NEGF;
    if (!ok2) s1[2] = NEGF;
    if (!ok3) s1[3] = NEGF;

    const f32x4 z = {0.f, 0.f, 0.f, 0.f};
    #pragma unroll 1
    for (int m = 0; m < 19; ++m) {
        float mx = fmaxf(fmaxf(fmaxf(s0[0], s0[1]), fmaxf(s0[2], s0[3])),
                         fmaxf(fmaxf(s1[0], s1[1]), fmaxf(s1[2], s1[3])));
        mx = fmaxf(mx, __shfl_xor(mx, 16, 64));
        mx = fmaxf(mx, __shfl_xor(mx, 32, 64));
        ABu B;
        B.u[0] = f2bf(__builtin_amdgcn_exp2f(s0[0] - mx));
        B.u[1] = f2bf(__builtin_amdgcn_exp2f(s0[1] - mx));
        B.u[2] = f2bf(__builtin_amdgcn_exp2f(s0[2] - mx));
        B.u[3] = f2bf(__builtin_amdgcn_exp2f(s0[3] - mx));
        B.u[4] = f2bf(__builtin_amdgcn_exp2f(s1[0] - mx));
        B.u[5] = f2bf(__builtin_amdgcn_exp2f(s1[1] - mx));
        B.u[6] = f2bf(__builtin_amdgcn_exp2f(s1[2] - mx));
        B.u[7] = f2bf(__builtin_amdgcn_exp2f(s1[3] - mx));
        f32x4 D0 = __builtin_amdgcn_mfma_f32_16x16x32_bf16(A0.b, B.b, z, 0, 0, 0);
        f32x4 D1 = __builtin_amdgcn_mfma_f32_16x16x32_bf16(A1.b, B.b, z, 0, 0, 0);
        const float* em = eb + (m + 1) * 33;
        #pragma unroll
        for (int i = 0; i < 4; ++i)
            s0[i] = mx + __builtin_amdgcn_logf(D0[i]) + em[i];
        s1[0] = ok0 ? (mx + __builtin_amdgcn_logf(D1[0]) + em[16]) : NEGF;
        s1[1] = ok1 ? (mx + __builtin_amdgcn_logf(D1[1]) + em[17]) : NEGF;
        s1[2] = ok2 ? (mx + __builtin_amdgcn_logf(D1[2]) + em[18]) : NEGF;
        s1[3] = ok3 ? (mx + __builtin_amdgcn_logf(D1[3]) + em[19]) : NEGF;
    }

    // logZ per column c
    float mx2 = fmaxf(fmaxf(fmaxf(s0[0], s0[1]), fmaxf(s0[2], s0[3])),
                      fmaxf(fmaxf(s1[0], s1[1]), fmaxf(s1[2], s1[3])));
    mx2 = fmaxf(mx2, __shfl_xor(mx2, 16, 64));
    mx2 = fmaxf(mx2, __shfl_xor(mx2, 32, 64));
    float sm = __builtin_amdgcn_exp2f(s0[0] - mx2) + __builtin_amdgcn_exp2f(s0[1] - mx2)
             + __builtin_amdgcn_exp2f(s0[2] - mx2) + __builtin_amdgcn_exp2f(s0[3] - mx2)
             + __builtin_amdgcn_exp2f(s1[0] - mx2) + __builtin_amdgcn_exp2f(s1[1] - mx2)
             + __builtin_amdgcn_exp2f(s1[2] - mx2) + __builtin_amdgcn_exp2f(s1[3] - mx2);
    sm += __shfl_xor(sm, 16, 64);
    sm += __shfl_xor(sm, 32, 64);
    const float logZ2 = mx2 + __builtin_amdgcn_logf(sm);

    float v = (g == 0) ? LN2 * logZ2 : 0.f;
    #pragma unroll
    for (int d = 1; d <= 32; d <<= 1) v += __shfl_xor(v, d, 64);
    if (l == 0) atomicAdd(out, v);
}

extern "C" void kernel_launch(void* const* d_in, const int* in_sizes, int n_in,
                              void* d_out, int out_size, void* d_ws, size_t ws_size,
                              hipStream_t stream) {
    const float* X = (const float*)d_in[0];
    const int*   Y = (const int*)d_in[1];
    const float* W = (const float*)d_in[2];
    const float* T = (const float*)d_in[3];
    float* out = (float*)d_out;

    const int B = in_sizes[1] / 20;        // 8192
    const int nblocks = B / 16;            // 512

    hipMemsetAsync(out, 0, sizeof(float), stream);
    crf_kernel<<<nblocks, 256, 0, stream>>>(X, Y, W, T, out, B);
}